// Round 6
// baseline (1320.331 us; speedup 1.0000x reference)
//
#include <hip/hip_runtime.h>
#include <hip/hip_bf16.h>
#include <math.h>

#define DD 4096
#define BB 2048
#define RCAP 32
#define KP (3*DD)   // packed K dimension (hi|mid|lo)

#define PRNG_PARTITIONABLE 1

struct KeyArgs { unsigned a0[RCAP]; unsigned a1[RCAP]; };

__host__ __device__ static inline void tf2x32(unsigned k0, unsigned k1,
                                              unsigned x0, unsigned x1,
                                              unsigned &o0, unsigned &o1) {
  const unsigned k2 = k0 ^ k1 ^ 0x1BD11BDAu;
#define TFR(r) { x0 += x1; x1 = (x1 << (r)) | (x1 >> (32 - (r))); x1 ^= x0; }
  x0 += k0; x1 += k1;
  TFR(13) TFR(15) TFR(26) TFR(6)
  x0 += k1; x1 += k2 + 1u;
  TFR(17) TFR(29) TFR(16) TFR(24)
  x0 += k2; x1 += k0 + 2u;
  TFR(13) TFR(15) TFR(26) TFR(6)
  x0 += k0; x1 += k1 + 3u;
  TFR(17) TFR(29) TFR(16) TFR(24)
  x0 += k1; x1 += k2 + 4u;
  TFR(13) TFR(15) TFR(26) TFR(6)
  x0 += k2; x1 += k0 + 5u;
#undef TFR
  o0 = x0; o1 = x1;
}

__device__ static inline unsigned jax_bits_elem(unsigned k0, unsigned k1,
                                                unsigned n, unsigned sz) {
#if PRNG_PARTITIONABLE
  (void)sz;
  unsigned o0, o1; tf2x32(k0, k1, 0u, n, o0, o1);
  return o0 ^ o1;
#else
  const unsigned half = sz >> 1;
  unsigned o0, o1;
  if (n < half) { tf2x32(k0, k1, n, n + half, o0, o1); return o0; }
  else          { tf2x32(k0, k1, n - half, n, o0, o1); return o1; }
#endif
}

__device__ static inline float jax_uniform01(unsigned bits) {
  return __uint_as_float((bits >> 9) | 0x3f800000u) - 1.0f;
}

__device__ static inline float jax_gumbel(unsigned bits) {
  float f = jax_uniform01(bits);
  float u = (f > 0.0f) ? f : 1.17549435e-38f;
  return -logf(-logf(u));
}

__device__ static inline unsigned short f2bf(float f) {
  unsigned u = __float_as_uint(f);
  unsigned r = (u + 0x7fffu + ((u >> 16) & 1u)) >> 16;
  return (unsigned short)r;
}
__device__ static inline float bf2f(unsigned short s) {
  return __uint_as_float(((unsigned)s) << 16);
}

// ---------------- K0a: split W into (hi|mid|lo) packed bf16 [DD][KP] ---------
__global__ __launch_bounds__(256) void k0_split(
    const float* __restrict__ W, unsigned short* __restrict__ Wp)
{
  const int t = blockIdx.x * 256 + threadIdx.x;
  const long long base = (long long)t * 4;
  const int n = (int)(base >> 12);
  const int k = (int)(base & 4095);
  const float4 w = *(const float4*)(W + base);
  float wv[4] = {w.x, w.y, w.z, w.w};
  unsigned short hi[4], mid[4], lo[4];
#pragma unroll
  for (int i = 0; i < 4; ++i) {
    unsigned short h1 = f2bf(wv[i]);
    float r1 = wv[i] - bf2f(h1);
    unsigned short h2 = f2bf(r1);
    float r2 = r1 - bf2f(h2);
    unsigned short h3 = f2bf(r2);
    hi[i] = h1; mid[i] = h2; lo[i] = h3;
  }
  const long long rb = (long long)n * KP;
  uint2 vh = make_uint2((unsigned)hi[0] | ((unsigned)hi[1] << 16),
                        (unsigned)hi[2] | ((unsigned)hi[3] << 16));
  uint2 vm = make_uint2((unsigned)mid[0] | ((unsigned)mid[1] << 16),
                        (unsigned)mid[2] | ((unsigned)mid[3] << 16));
  uint2 vl = make_uint2((unsigned)lo[0] | ((unsigned)lo[1] << 16),
                        (unsigned)lo[2] | ((unsigned)lo[3] << 16));
  *(uint2*)(Wp + rb + 0 * DD + k) = vh;
  *(uint2*)(Wp + rb + 1 * DD + k) = vm;
  *(uint2*)(Wp + rb + 2 * DD + k) = vl;
}

// ---------------- K0b: x fp32(0/1) -> bf16 -----------------------------------
__global__ __launch_bounds__(256) void k0_x(
    const float* __restrict__ x, unsigned short* __restrict__ xb)
{
  const int t = blockIdx.x * 256 + threadIdx.x;
  const long long base = (long long)t * 4;
  const float4 w = *(const float4*)(x + base);
  uint2 v = make_uint2((unsigned)f2bf(w.x) | ((unsigned)f2bf(w.y) << 16),
                       (unsigned)f2bf(w.z) | ((unsigned)f2bf(w.w) << 16));
  *(uint2*)(xb + base) = v;
}

// ---------------- K1: h = x @ (Whi+Wmid+Wlo) via bf16 MFMA -------------------
typedef __attribute__((ext_vector_type(8))) short bf16x8;
typedef __attribute__((ext_vector_type(4))) float f32x4;

#define TM 128
#define TN 128
#define TBK 64

__device__ __forceinline__ void gload16(const void* g, void* l) {
  __builtin_amdgcn_global_load_lds(
      (const __attribute__((address_space(1))) unsigned int*)g,
      (__attribute__((address_space(3))) unsigned int*)l,
      16, 0, 0);
}

__global__ __launch_bounds__(256) void k1_mfma(
    const unsigned short* __restrict__ xb,   // [BB][DD] bf16
    const unsigned short* __restrict__ Wp,   // [DD][KP] bf16 (B^T by symmetry)
    float* __restrict__ h)                   // [BB][DD] fp32
{
  __shared__ unsigned short sA[TM * TBK];    // [128][64] XOR-swizzled
  __shared__ unsigned short sB[TN * TBK];

  const int bid = blockIdx.x;                 // 512 blocks
  const int swz = (bid & 7) * 64 + (bid >> 3);   // bijective XCD swizzle
  const int nbx = DD / TN;                    // 32
  const int bm = (swz / nbx) * TM;
  const int bn = (swz % nbx) * TN;

  const int tid = threadIdx.x;
  const int wid = tid >> 6;
  const int lane = tid & 63;
  const int wr = wid >> 1, wc = wid & 1;

  f32x4 acc[4][4], carry[4][4];
  const f32x4 z4 = {0.f, 0.f, 0.f, 0.f};
#pragma unroll
  for (int i = 0; i < 4; ++i)
#pragma unroll
    for (int j = 0; j < 4; ++j) { acc[i][j] = z4; carry[i][j] = z4; }

  const int arow = wid * 32 + (lane >> 3);
  const int asrccol = ((lane & 7) * 16) ^ ((lane >> 3) << 4);  // bytes, pre-swizzled
  const char* gA = (const char*)xb + (long long)(bm + arow) * (DD * 2) + asrccol;
  const char* gB = (const char*)Wp + (long long)(bn + arow) * (KP * 2) + asrccol;
  char* lA = (char*)sA + (wid * 32) * 128;
  char* lB = (char*)sB + (wid * 32) * 128;

  const int rbaseA = wr * 64 + (lane & 15);
  const int rbaseB = wc * 64 + (lane & 15);
  int colx[2];
#pragma unroll
  for (int hh = 0; hh < 2; ++hh)
    colx[hh] = (hh * 64 + ((lane >> 4) * 16)) ^ ((lane & 7) << 4);

  for (int kt = 0; kt < KP / TBK; ++kt) {
    const int k0m = (kt * TBK) & (DD - 1);      // A wraps every DD (x reused per term)
    const char* pa = gA + k0m * 2;
    const char* pb = gB + (long long)kt * (TBK * 2);
#pragma unroll
    for (int u = 0; u < 4; ++u)
      gload16(pa + (long long)u * 8 * (DD * 2), lA + u * 8 * 128);
#pragma unroll
    for (int u = 0; u < 4; ++u)
      gload16(pb + (long long)u * 8 * (KP * 2), lB + u * 8 * 128);
    __syncthreads();

    bf16x8 af[2][4], bff[2][4];
#pragma unroll
    for (int hh = 0; hh < 2; ++hh) {
#pragma unroll
      for (int i = 0; i < 4; ++i) {
        af[hh][i]  = *(const bf16x8*)((const char*)sA + (rbaseA + i * 16) * 128 + colx[hh]);
        bff[hh][i] = *(const bf16x8*)((const char*)sB + (rbaseB + i * 16) * 128 + colx[hh]);
      }
    }
#pragma unroll
    for (int hh = 0; hh < 2; ++hh)
#pragma unroll
      for (int i = 0; i < 4; ++i)
#pragma unroll
        for (int j = 0; j < 4; ++j)
          acc[i][j] = __builtin_amdgcn_mfma_f32_16x16x32_bf16(af[hh][i], bff[hh][j], acc[i][j], 0, 0, 0);
    __syncthreads();

    if ((kt & 7) == 7) {
#pragma unroll
      for (int i = 0; i < 4; ++i)
#pragma unroll
        for (int j = 0; j < 4; ++j) { carry[i][j] += acc[i][j]; acc[i][j] = z4; }
    }
  }

#pragma unroll
  for (int i = 0; i < 4; ++i)
#pragma unroll
    for (int j = 0; j < 4; ++j)
#pragma unroll
      for (int q = 0; q < 4; ++q) {
        const int row = bm + wr * 64 + i * 16 + (lane >> 4) * 4 + q;
        const int col = bn + wc * 64 + j * 16 + (lane & 15);
        h[(long long)row * DD + col] = carry[i][j][q];
      }
}

// ---------------- K2: per-row stats + 32-step forward Gumbel scan ------------
__global__ __launch_bounds__(256) void k2_forward(
    const float* __restrict__ x, const float* __restrict__ b,
    const float* __restrict__ h, KeyArgs keys,
    int* __restrict__ idx_all, int* __restrict__ radius_out,
    double* __restrict__ logfwd_out)
{
  const int r = blockIdx.x;
  const int tid = threadIdx.x;
  __shared__ float sc[DD];
  __shared__ unsigned char ch[DD];
  __shared__ double redD[256];
  __shared__ int   redI[256];
  __shared__ double sM, sS, sScore, sAcc;
  __shared__ int sRad;
  __shared__ int sIdxHist[RCAP];

  double pMax = -1e300, pScore = 0.0;
  for (int k = 0; k < DD / 256; ++k) {
    const int j = tid + 256 * k;
    const float xv = x[r * DD + j];
    const float hv = h[r * DD + j];
    const float bv = b[j];
    const double grad = (double)hv + (double)bv;
    const double scd = (1.0 - 2.0 * (double)xv) * grad * 0.5;
    const float scf = (float)scd;
    sc[j] = scf;
    ch[j] = 0;
    pMax = fmax(pMax, (double)scf);
    pScore += (double)xv * (0.5 * (double)hv + (double)bv);
  }
  redD[tid] = pMax; __syncthreads();
  for (int s = 128; s > 0; s >>= 1) {
    if (tid < s) redD[tid] = fmax(redD[tid], redD[tid + s]);
    __syncthreads();
  }
  if (tid == 0) sM = redD[0];
  __syncthreads();
  const double M = sM;
  double pSum = 0.0;
  for (int k = 0; k < DD / 256; ++k) {
    const int j = tid + 256 * k;
    pSum += exp((double)sc[j] - M);
  }
  redD[tid] = pSum; __syncthreads();
  for (int s = 128; s > 0; s >>= 1) {
    if (tid < s) redD[tid] += redD[tid + s];
    __syncthreads();
  }
  if (tid == 0) sS = redD[0];
  __syncthreads();
  const double lse = M + log(sS);
  redD[tid] = pScore; __syncthreads();
  for (int s = 128; s > 0; s >>= 1) {
    if (tid < s) redD[tid] += redD[tid + s];
    __syncthreads();
  }
  if (tid == 0) sScore = redD[0];
  __syncthreads();
  const double L02 = log((double)0.02f);
  int pc = 0;
  for (int k = 0; k < DD / 256; ++k) {
    const int j = tid + 256 * k;
    pc += ((double)sc[j] - lse > L02) ? 1 : 0;
  }
  redI[tid] = pc; __syncthreads();
  for (int s = 128; s > 0; s >>= 1) {
    if (tid < s) redI[tid] += redI[tid + s];
    __syncthreads();
  }
  if (tid == 0) { sRad = redI[0] + 1; sAcc = 0.0; }
  __syncthreads();

  const unsigned base = (unsigned)(r * DD);
  for (int t = 0; t < RCAP; ++t) {
    const unsigned K0 = keys.a0[t], K1 = keys.a1[t];
    double bestV = -1e300; int bestI = 0;
    for (int k = 0; k < DD / 256; ++k) {
      const int j = tid + 256 * k;
      if (ch[j]) continue;
      const unsigned bits = jax_bits_elem(K0, K1, base + (unsigned)j, (unsigned)(BB * DD));
      const float g = jax_gumbel(bits);
      const double v = (double)sc[j] + (double)g;
      if (v > bestV) { bestV = v; bestI = j; }
    }
    redD[tid] = bestV; redI[tid] = bestI; __syncthreads();
    for (int s = 128; s > 0; s >>= 1) {
      if (tid < s) {
        const double v2 = redD[tid + s]; const int i2 = redI[tid + s];
        if (v2 > redD[tid] || (v2 == redD[tid] && i2 < redI[tid])) {
          redD[tid] = v2; redI[tid] = i2;
        }
      }
      __syncthreads();
    }
    if (tid == 0) {
      const int idx = redI[0];
      const double scd = (double)sc[idx];
      const double logp = scd - (M + log(sS));
      if (t < sRad) sAcc += logp;
      sS -= exp(scd - M);
      sIdxHist[t] = idx;
      ch[idx] = 1;
    }
    __syncthreads();
  }
  if (tid == 0) {
    radius_out[r] = sRad;
    logfwd_out[r] = sAcc + sScore;
  }
  if (tid < RCAP) idx_all[r * RCAP + tid] = sIdxHist[tid];
}

// ---------------- K3: rank-update, backward logp, accept, output -------------
__global__ __launch_bounds__(256) void k3_backward(
    const float* __restrict__ x, const float* __restrict__ W,
    const float* __restrict__ b, const float* __restrict__ h,
    const int* __restrict__ idx_all, const int* __restrict__ radius,
    const double* __restrict__ logfwd, unsigned ak0, unsigned ak1,
    float* __restrict__ out)
{
  const int r = blockIdx.x;
  const int tid = threadIdx.x;
  __shared__ double scY[DD];
  __shared__ float yR[DD];
  __shared__ double redD[256];
  __shared__ int fl[RCAP];
  __shared__ double fdel[RCAP];
  __shared__ double vals[RCAP];
  __shared__ double sM, sS, sScore;
  __shared__ int sAccFlag;
  const int rad = radius[r];
  const int nf = rad < RCAP ? rad : RCAP;
  if (tid < RCAP) {
    const int idx = idx_all[r * RCAP + tid];
    fl[tid] = idx;
    fdel[tid] = 1.0 - 2.0 * (double)x[r * DD + idx];
  }
  __syncthreads();
  double pM = -1e300, pScore = 0.0;
  for (int k = 0; k < DD / 256; ++k) {
    const int j = tid + 256 * k;
    double hy = (double)h[r * DD + j];
    for (int f = 0; f < nf; ++f) hy += fdel[f] * (double)W[fl[f] * DD + j];
    const float xv = x[r * DD + j];
    bool isf = false;
    for (int f = 0; f < nf; ++f) isf = isf || (fl[f] == j);
    const float yv = isf ? (1.0f - xv) : xv;
    yR[j] = yv;
    const double bv = (double)b[j];
    const double scd = (1.0 - 2.0 * (double)yv) * (hy + bv) * 0.5;
    scY[j] = scd;
    pM = fmax(pM, scd);
    pScore += (double)yv * (0.5 * hy + bv);
  }
  redD[tid] = pM; __syncthreads();
  for (int s = 128; s > 0; s >>= 1) {
    if (tid < s) redD[tid] = fmax(redD[tid], redD[tid + s]);
    __syncthreads();
  }
  if (tid == 0) sM = redD[0];
  __syncthreads();
  const double M = sM;
  double pS = 0.0;
  for (int k = 0; k < DD / 256; ++k) {
    const int j = tid + 256 * k;
    pS += exp(scY[j] - M);
  }
  redD[tid] = pS; __syncthreads();
  for (int s = 128; s > 0; s >>= 1) {
    if (tid < s) redD[tid] += redD[tid + s];
    __syncthreads();
  }
  if (tid == 0) sS = redD[0];
  __syncthreads();
  redD[tid] = pScore; __syncthreads();
  for (int s = 128; s > 0; s >>= 1) {
    if (tid < s) redD[tid] += redD[tid + s];
    __syncthreads();
  }
  if (tid == 0) sScore = redD[0];
  if (tid < RCAP) vals[tid] = scY[fl[tid]];
  __syncthreads();
  if (tid == 0) {
    double S = sS, accum = 0.0;
    for (int t = RCAP - 1; t >= 0; --t) {
      const double lp = vals[t] - (M + log(S));
      if (t < rad) accum += lp;
      S -= exp(vals[t] - M);
    }
    const double log_bwd = accum + sScore;
    const double log_acc = log_bwd - logfwd[r];
    const unsigned bits = jax_bits_elem(ak0, ak1, (unsigned)r, (unsigned)BB);
    const float u = jax_uniform01(bits);
    sAccFlag = (exp(log_acc) >= (double)u) ? 1 : 0;
  }
  __syncthreads();
  const int acc = sAccFlag;
  for (int k = 0; k < DD / 256; ++k) {
    const int j = tid + 256 * k;
    out[r * DD + j] = acc ? yR[j] : x[r * DD + j];
  }
}

// ---------------- host launcher ----------------------------------------------
extern "C" void kernel_launch(void* const* d_in, const int* in_sizes, int n_in,
                              void* d_out, int out_size, void* d_ws, size_t ws_size,
                              hipStream_t stream)
{
  const float* x = (const float*)d_in[0];
  const float* W = (const float*)d_in[1];
  const float* b = (const float*)d_in[2];
  float* out = (float*)d_out;
  char* wsb = (char*)d_ws;
  float*          h       = (float*)wsb;                                  // 33554432 B
  unsigned short* Wp      = (unsigned short*)(wsb + 33554432LL);          // 100663296 B
  unsigned short* xbf     = (unsigned short*)(wsb + 134217728LL);         // 16777216 B
  double*         logfwd  = (double*)(wsb + 150994944LL);                 // 16384 B
  int*            idx_all = (int*)(wsb + 150994944LL + 16384);            // 262144 B
  int*            radius  = (int*)(wsb + 150994944LL + 16384 + 262144);   // 8192 B

  KeyArgs ka;
  unsigned ak0 = 0, ak1 = 0;
#if PRNG_PARTITIONABLE
  for (int i = 0; i <= RCAP; ++i) {
    unsigned o0, o1; tf2x32(0u, 42u, 0u, (unsigned)i, o0, o1);
    if (i < RCAP) { ka.a0[i] = o0; ka.a1[i] = o1; }
    else { ak0 = o0; ak1 = o1; }
  }
#else
  {
    unsigned flat[66];
    for (int i = 0; i < 33; ++i) {
      unsigned o0, o1; tf2x32(0u, 42u, (unsigned)i, (unsigned)(i + 33), o0, o1);
      flat[i] = o0; flat[33 + i] = o1;
    }
    for (int t = 0; t < RCAP; ++t) { ka.a0[t] = flat[2 * t]; ka.a1[t] = flat[2 * t + 1]; }
    ak0 = flat[64]; ak1 = flat[65];
  }
#endif

  hipLaunchKernelGGL(k0_split, dim3(DD * DD / 1024), dim3(256), 0, stream, W, Wp);
  hipLaunchKernelGGL(k0_x, dim3(BB * DD / 1024), dim3(256), 0, stream, x, xbf);
  hipLaunchKernelGGL(k1_mfma, dim3((BB / TM) * (DD / TN)), dim3(256), 0, stream, xbf, Wp, h);
  hipLaunchKernelGGL(k2_forward, dim3(BB), dim3(256), 0, stream,
                     x, b, h, ka, idx_all, radius, logfwd);
  hipLaunchKernelGGL(k3_backward, dim3(BB), dim3(256), 0, stream,
                     x, W, b, h, idx_all, radius, logfwd, ak0, ak1, out);
}

// Round 9
// 1314.620 us; speedup vs baseline: 1.0043x; 1.0043x over previous
//
#include <hip/hip_runtime.h>
#include <hip/hip_bf16.h>
#include <math.h>

#define DD 4096
#define BB 2048
#define RCAP 32
#define KP (3*DD)   // packed K dimension (hi|mid|lo)

#define PRNG_PARTITIONABLE 1

struct KeyArgs { unsigned a0[RCAP]; unsigned a1[RCAP]; };

__host__ __device__ static inline void tf2x32(unsigned k0, unsigned k1,
                                              unsigned x0, unsigned x1,
                                              unsigned &o0, unsigned &o1) {
  const unsigned k2 = k0 ^ k1 ^ 0x1BD11BDAu;
#define TFR(r) { x0 += x1; x1 = (x1 << (r)) | (x1 >> (32 - (r))); x1 ^= x0; }
  x0 += k0; x1 += k1;
  TFR(13) TFR(15) TFR(26) TFR(6)
  x0 += k1; x1 += k2 + 1u;
  TFR(17) TFR(29) TFR(16) TFR(24)
  x0 += k2; x1 += k0 + 2u;
  TFR(13) TFR(15) TFR(26) TFR(6)
  x0 += k0; x1 += k1 + 3u;
  TFR(17) TFR(29) TFR(16) TFR(24)
  x0 += k1; x1 += k2 + 4u;
  TFR(13) TFR(15) TFR(26) TFR(6)
  x0 += k2; x1 += k0 + 5u;
#undef TFR
  o0 = x0; o1 = x1;
}

__device__ static inline unsigned jax_bits_elem(unsigned k0, unsigned k1,
                                                unsigned n, unsigned sz) {
#if PRNG_PARTITIONABLE
  (void)sz;
  unsigned o0, o1; tf2x32(k0, k1, 0u, n, o0, o1);
  return o0 ^ o1;
#else
  const unsigned half = sz >> 1;
  unsigned o0, o1;
  if (n < half) { tf2x32(k0, k1, n, n + half, o0, o1); return o0; }
  else          { tf2x32(k0, k1, n - half, n, o0, o1); return o1; }
#endif
}

__device__ static inline float jax_uniform01(unsigned bits) {
  return __uint_as_float((bits >> 9) | 0x3f800000u) - 1.0f;
}

__device__ static inline float jax_gumbel(unsigned bits) {
  float f = jax_uniform01(bits);
  float u = (f > 0.0f) ? f : 1.17549435e-38f;
  return -logf(-logf(u));
}

__device__ static inline unsigned short f2bf(float f) {
  unsigned u = __float_as_uint(f);
  unsigned r = (u + 0x7fffu + ((u >> 16) & 1u)) >> 16;
  return (unsigned short)r;
}
__device__ static inline float bf2f(unsigned short s) {
  return __uint_as_float(((unsigned)s) << 16);
}

// ---------------- K0: fused prep — split W into (hi|mid|lo) bf16 AND x->bf16 -
// Blocks [0, 16384): W split part.  Blocks [16384, 24576): x convert part.
__global__ __launch_bounds__(256) void k0_prep(
    const float* __restrict__ x, const float* __restrict__ W,
    unsigned short* __restrict__ Wp, unsigned short* __restrict__ xb)
{
  const int bid = blockIdx.x;
  if (bid < (DD * DD / 1024)) {
    const int t = bid * 256 + threadIdx.x;
    const long long base = (long long)t * 4;
    const int n = (int)(base >> 12);
    const int k = (int)(base & 4095);
    const float4 w = *(const float4*)(W + base);
    float wv[4] = {w.x, w.y, w.z, w.w};
    unsigned short hi[4], mid[4], lo[4];
#pragma unroll
    for (int i = 0; i < 4; ++i) {
      unsigned short h1 = f2bf(wv[i]);
      float r1 = wv[i] - bf2f(h1);
      unsigned short h2 = f2bf(r1);
      float r2 = r1 - bf2f(h2);
      unsigned short h3 = f2bf(r2);
      hi[i] = h1; mid[i] = h2; lo[i] = h3;
    }
    const long long rb = (long long)n * KP;
    uint2 vh = make_uint2((unsigned)hi[0] | ((unsigned)hi[1] << 16),
                          (unsigned)hi[2] | ((unsigned)hi[3] << 16));
    uint2 vm = make_uint2((unsigned)mid[0] | ((unsigned)mid[1] << 16),
                          (unsigned)mid[2] | ((unsigned)mid[3] << 16));
    uint2 vl = make_uint2((unsigned)lo[0] | ((unsigned)lo[1] << 16),
                          (unsigned)lo[2] | ((unsigned)lo[3] << 16));
    *(uint2*)(Wp + rb + 0 * DD + k) = vh;
    *(uint2*)(Wp + rb + 1 * DD + k) = vm;
    *(uint2*)(Wp + rb + 2 * DD + k) = vl;
  } else {
    const int t = (bid - (DD * DD / 1024)) * 256 + threadIdx.x;
    const long long base = (long long)t * 4;
    const float4 w = *(const float4*)(x + base);
    uint2 v = make_uint2((unsigned)f2bf(w.x) | ((unsigned)f2bf(w.y) << 16),
                         (unsigned)f2bf(w.z) | ((unsigned)f2bf(w.w) << 16));
    *(uint2*)(xb + base) = v;
  }
}

// ---------------- K1: h = x @ (Whi+Wmid+Wlo) via bf16 MFMA -------------------
typedef __attribute__((ext_vector_type(8))) short bf16x8;
typedef __attribute__((ext_vector_type(4))) float f32x4;

#define TM 128
#define TN 128
#define TBK 64

__device__ __forceinline__ void gload16(const void* g, void* l) {
  __builtin_amdgcn_global_load_lds(
      (const __attribute__((address_space(1))) unsigned int*)g,
      (__attribute__((address_space(3))) unsigned int*)l,
      16, 0, 0);
}

__global__ __launch_bounds__(256) void k1_mfma(
    const unsigned short* __restrict__ xb,   // [BB][DD] bf16
    const unsigned short* __restrict__ Wp,   // [DD][KP] bf16 (B^T by symmetry)
    float* __restrict__ h)                   // [BB][DD] fp32
{
  __shared__ unsigned short sA[TM * TBK];    // [128][64] XOR-swizzled
  __shared__ unsigned short sB[TN * TBK];

  const int bid = blockIdx.x;                 // 512 blocks
  const int swz = (bid & 7) * 64 + (bid >> 3);   // bijective XCD swizzle
  const int nbx = DD / TN;                    // 32
  const int bm = (swz / nbx) * TM;
  const int bn = (swz % nbx) * TN;

  const int tid = threadIdx.x;
  const int wid = tid >> 6;
  const int lane = tid & 63;
  const int wr = wid >> 1, wc = wid & 1;

  f32x4 acc[4][4], carry[4][4];
  const f32x4 z4 = {0.f, 0.f, 0.f, 0.f};
#pragma unroll
  for (int i = 0; i < 4; ++i)
#pragma unroll
    for (int j = 0; j < 4; ++j) { acc[i][j] = z4; carry[i][j] = z4; }

  const int arow = wid * 32 + (lane >> 3);
  const int asrccol = ((lane & 7) * 16) ^ ((lane >> 3) << 4);  // bytes, pre-swizzled
  const char* gA = (const char*)xb + (long long)(bm + arow) * (DD * 2) + asrccol;
  const char* gB = (const char*)Wp + (long long)(bn + arow) * (KP * 2) + asrccol;
  char* lA = (char*)sA + (wid * 32) * 128;
  char* lB = (char*)sB + (wid * 32) * 128;

  const int rbaseA = wr * 64 + (lane & 15);
  const int rbaseB = wc * 64 + (lane & 15);
  int colx[2];
#pragma unroll
  for (int hh = 0; hh < 2; ++hh)
    colx[hh] = (hh * 64 + ((lane >> 4) * 16)) ^ ((lane & 7) << 4);

  for (int kt = 0; kt < KP / TBK; ++kt) {
    const int k0m = (kt * TBK) & (DD - 1);      // A wraps every DD (x reused per term)
    const char* pa = gA + k0m * 2;
    const char* pb = gB + (long long)kt * (TBK * 2);
#pragma unroll
    for (int u = 0; u < 4; ++u)
      gload16(pa + (long long)u * 8 * (DD * 2), lA + u * 8 * 128);
#pragma unroll
    for (int u = 0; u < 4; ++u)
      gload16(pb + (long long)u * 8 * (KP * 2), lB + u * 8 * 128);
    __syncthreads();

    bf16x8 af[2][4], bff[2][4];
#pragma unroll
    for (int hh = 0; hh < 2; ++hh) {
#pragma unroll
      for (int i = 0; i < 4; ++i) {
        af[hh][i]  = *(const bf16x8*)((const char*)sA + (rbaseA + i * 16) * 128 + colx[hh]);
        bff[hh][i] = *(const bf16x8*)((const char*)sB + (rbaseB + i * 16) * 128 + colx[hh]);
      }
    }
#pragma unroll
    for (int hh = 0; hh < 2; ++hh)
#pragma unroll
      for (int i = 0; i < 4; ++i)
#pragma unroll
        for (int j = 0; j < 4; ++j)
          acc[i][j] = __builtin_amdgcn_mfma_f32_16x16x32_bf16(af[hh][i], bff[hh][j], acc[i][j], 0, 0, 0);
    __syncthreads();

    if ((kt & 7) == 7) {
#pragma unroll
      for (int i = 0; i < 4; ++i)
#pragma unroll
        for (int j = 0; j < 4; ++j) { carry[i][j] += acc[i][j]; acc[i][j] = z4; }
    }
  }

#pragma unroll
  for (int i = 0; i < 4; ++i)
#pragma unroll
    for (int j = 0; j < 4; ++j)
#pragma unroll
      for (int q = 0; q < 4; ++q) {
        const int row = bm + wr * 64 + i * 16 + (lane >> 4) * 4 + q;
        const int col = bn + wc * 64 + j * 16 + (lane & 15);
        h[(long long)row * DD + col] = carry[i][j][q];
      }
}

// ---------------- K2: per-row stats + 32-step forward Gumbel scan ------------
__global__ __launch_bounds__(256) void k2_forward(
    const float* __restrict__ x, const float* __restrict__ b,
    const float* __restrict__ h, KeyArgs keys,
    int* __restrict__ idx_all, int* __restrict__ radius_out,
    double* __restrict__ logfwd_out)
{
  const int r = blockIdx.x;
  const int tid = threadIdx.x;
  __shared__ float sc[DD];
  __shared__ unsigned char ch[DD];
  __shared__ double redD[256];
  __shared__ int   redI[256];
  __shared__ double sM, sS, sScore, sAcc;
  __shared__ int sRad;
  __shared__ int sIdxHist[RCAP];

  double pMax = -1e300, pScore = 0.0;
  for (int k = 0; k < DD / 256; ++k) {
    const int j = tid + 256 * k;
    const float xv = x[r * DD + j];
    const float hv = h[r * DD + j];
    const float bv = b[j];
    const double grad = (double)hv + (double)bv;
    const double scd = (1.0 - 2.0 * (double)xv) * grad * 0.5;
    const float scf = (float)scd;
    sc[j] = scf;
    ch[j] = 0;
    pMax = fmax(pMax, (double)scf);
    pScore += (double)xv * (0.5 * (double)hv + (double)bv);
  }
  redD[tid] = pMax; __syncthreads();
  for (int s = 128; s > 0; s >>= 1) {
    if (tid < s) redD[tid] = fmax(redD[tid], redD[tid + s]);
    __syncthreads();
  }
  if (tid == 0) sM = redD[0];
  __syncthreads();
  const double M = sM;
  double pSum = 0.0;
  for (int k = 0; k < DD / 256; ++k) {
    const int j = tid + 256 * k;
    pSum += exp((double)sc[j] - M);
  }
  redD[tid] = pSum; __syncthreads();
  for (int s = 128; s > 0; s >>= 1) {
    if (tid < s) redD[tid] += redD[tid + s];
    __syncthreads();
  }
  if (tid == 0) sS = redD[0];
  __syncthreads();
  const double lse = M + log(sS);
  redD[tid] = pScore; __syncthreads();
  for (int s = 128; s > 0; s >>= 1) {
    if (tid < s) redD[tid] += redD[tid + s];
    __syncthreads();
  }
  if (tid == 0) sScore = redD[0];
  __syncthreads();
  const double L02 = log((double)0.02f);
  int pc = 0;
  for (int k = 0; k < DD / 256; ++k) {
    const int j = tid + 256 * k;
    pc += ((double)sc[j] - lse > L02) ? 1 : 0;
  }
  redI[tid] = pc; __syncthreads();
  for (int s = 128; s > 0; s >>= 1) {
    if (tid < s) redI[tid] += redI[tid + s];
    __syncthreads();
  }
  if (tid == 0) { sRad = redI[0] + 1; sAcc = 0.0; }
  __syncthreads();

  const unsigned base = (unsigned)(r * DD);
  for (int t = 0; t < RCAP; ++t) {
    const unsigned K0 = keys.a0[t], K1 = keys.a1[t];
    double bestV = -1e300; int bestI = 0;
    for (int k = 0; k < DD / 256; ++k) {
      const int j = tid + 256 * k;
      if (ch[j]) continue;
      const unsigned bits = jax_bits_elem(K0, K1, base + (unsigned)j, (unsigned)(BB * DD));
      const float g = jax_gumbel(bits);
      const double v = (double)sc[j] + (double)g;
      if (v > bestV) { bestV = v; bestI = j; }
    }
    redD[tid] = bestV; redI[tid] = bestI; __syncthreads();
    for (int s = 128; s > 0; s >>= 1) {
      if (tid < s) {
        const double v2 = redD[tid + s]; const int i2 = redI[tid + s];
        if (v2 > redD[tid] || (v2 == redD[tid] && i2 < redI[tid])) {
          redD[tid] = v2; redI[tid] = i2;
        }
      }
      __syncthreads();
    }
    if (tid == 0) {
      const int idx = redI[0];
      const double scd = (double)sc[idx];
      const double logp = scd - (M + log(sS));
      if (t < sRad) sAcc += logp;
      sS -= exp(scd - M);
      sIdxHist[t] = idx;
      ch[idx] = 1;
    }
    __syncthreads();
  }
  if (tid == 0) {
    radius_out[r] = sRad;
    logfwd_out[r] = sAcc + sScore;
  }
  if (tid < RCAP) idx_all[r * RCAP + tid] = sIdxHist[tid];
}

// ---------------- K3: rank-update, backward logp, accept, output -------------
__global__ __launch_bounds__(256) void k3_backward(
    const float* __restrict__ x, const float* __restrict__ W,
    const float* __restrict__ b, const float* __restrict__ h,
    const int* __restrict__ idx_all, const int* __restrict__ radius,
    const double* __restrict__ logfwd, unsigned ak0, unsigned ak1,
    float* __restrict__ out)
{
  const int r = blockIdx.x;
  const int tid = threadIdx.x;
  __shared__ double scY[DD];
  __shared__ float yR[DD];
  __shared__ double redD[256];
  __shared__ int fl[RCAP];
  __shared__ double fdel[RCAP];
  __shared__ double vals[RCAP];
  __shared__ double sM, sS, sScore;
  __shared__ int sAccFlag;
  const int rad = radius[r];
  const int nf = rad < RCAP ? rad : RCAP;
  if (tid < RCAP) {
    const int idx = idx_all[r * RCAP + tid];
    fl[tid] = idx;
    fdel[tid] = 1.0 - 2.0 * (double)x[r * DD + idx];
  }
  __syncthreads();
  double pM = -1e300, pScore = 0.0;
  for (int k = 0; k < DD / 256; ++k) {
    const int j = tid + 256 * k;
    double hy = (double)h[r * DD + j];
    for (int f = 0; f < nf; ++f) hy += fdel[f] * (double)W[fl[f] * DD + j];
    const float xv = x[r * DD + j];
    bool isf = false;
    for (int f = 0; f < nf; ++f) isf = isf || (fl[f] == j);
    const float yv = isf ? (1.0f - xv) : xv;
    yR[j] = yv;
    const double bv = (double)b[j];
    const double scd = (1.0 - 2.0 * (double)yv) * (hy + bv) * 0.5;
    scY[j] = scd;
    pM = fmax(pM, scd);
    pScore += (double)yv * (0.5 * hy + bv);
  }
  redD[tid] = pM; __syncthreads();
  for (int s = 128; s > 0; s >>= 1) {
    if (tid < s) redD[tid] = fmax(redD[tid], redD[tid + s]);
    __syncthreads();
  }
  if (tid == 0) sM = redD[0];
  __syncthreads();
  const double M = sM;
  double pS = 0.0;
  for (int k = 0; k < DD / 256; ++k) {
    const int j = tid + 256 * k;
    pS += exp(scY[j] - M);
  }
  redD[tid] = pS; __syncthreads();
  for (int s = 128; s > 0; s >>= 1) {
    if (tid < s) redD[tid] += redD[tid + s];
    __syncthreads();
  }
  if (tid == 0) sS = redD[0];
  __syncthreads();
  redD[tid] = pScore; __syncthreads();
  for (int s = 128; s > 0; s >>= 1) {
    if (tid < s) redD[tid] += redD[tid + s];
    __syncthreads();
  }
  if (tid == 0) sScore = redD[0];
  if (tid < RCAP) vals[tid] = scY[fl[tid]];
  __syncthreads();
  if (tid == 0) {
    double S = sS, accum = 0.0;
    for (int t = RCAP - 1; t >= 0; --t) {
      const double lp = vals[t] - (M + log(S));
      if (t < rad) accum += lp;
      S -= exp(vals[t] - M);
    }
    const double log_bwd = accum + sScore;
    const double log_acc = log_bwd - logfwd[r];
    const unsigned bits = jax_bits_elem(ak0, ak1, (unsigned)r, (unsigned)BB);
    const float u = jax_uniform01(bits);
    sAccFlag = (exp(log_acc) >= (double)u) ? 1 : 0;
  }
  __syncthreads();
  const int acc = sAccFlag;
  for (int k = 0; k < DD / 256; ++k) {
    const int j = tid + 256 * k;
    out[r * DD + j] = acc ? yR[j] : x[r * DD + j];
  }
}

// ---------------- host launcher ----------------------------------------------
extern "C" void kernel_launch(void* const* d_in, const int* in_sizes, int n_in,
                              void* d_out, int out_size, void* d_ws, size_t ws_size,
                              hipStream_t stream)
{
  const float* x = (const float*)d_in[0];
  const float* W = (const float*)d_in[1];
  const float* b = (const float*)d_in[2];
  float* out = (float*)d_out;
  char* wsb = (char*)d_ws;
  float*          h       = (float*)wsb;                                  // 33554432 B
  unsigned short* Wp      = (unsigned short*)(wsb + 33554432LL);          // 100663296 B
  unsigned short* xbf     = (unsigned short*)(wsb + 134217728LL);         // 16777216 B
  double*         logfwd  = (double*)(wsb + 150994944LL);                 // 16384 B
  int*            idx_all = (int*)(wsb + 150994944LL + 16384);            // 262144 B
  int*            radius  = (int*)(wsb + 150994944LL + 16384 + 262144);   // 8192 B

  KeyArgs ka;
  unsigned ak0 = 0, ak1 = 0;
#if PRNG_PARTITIONABLE
  for (int i = 0; i <= RCAP; ++i) {
    unsigned o0, o1; tf2x32(0u, 42u, 0u, (unsigned)i, o0, o1);
    if (i < RCAP) { ka.a0[i] = o0; ka.a1[i] = o1; }
    else { ak0 = o0; ak1 = o1; }
  }
#else
  {
    unsigned flat[66];
    for (int i = 0; i < 33; ++i) {
      unsigned o0, o1; tf2x32(0u, 42u, (unsigned)i, (unsigned)(i + 33), o0, o1);
      flat[i] = o0; flat[33 + i] = o1;
    }
    for (int t = 0; t < RCAP; ++t) { ka.a0[t] = flat[2 * t]; ka.a1[t] = flat[2 * t + 1]; }
    ak0 = flat[64]; ak1 = flat[65];
  }
#endif

  hipLaunchKernelGGL(k0_prep, dim3(DD * DD / 1024 + BB * DD / 1024), dim3(256), 0, stream,
                     x, W, Wp, xbf);
  hipLaunchKernelGGL(k1_mfma, dim3((BB / TM) * (DD / TN)), dim3(256), 0, stream, xbf, Wp, h);
  hipLaunchKernelGGL(k2_forward, dim3(BB), dim3(256), 0, stream,
                     x, b, h, ka, idx_all, radius, logfwd);
  hipLaunchKernelGGL(k3_backward, dim3(BB), dim3(256), 0, stream,
                     x, W, b, h, idx_all, radius, logfwd, ak0, ak1, out);
}